// Round 1
// baseline (431.126 us; speedup 1.0000x reference)
//
#include <hip/hip_runtime.h>
#include <hip/hip_bf16.h>

#define NS 32768          // B*S samples
#define FFN 2048
#define EMB 512
#define KDIM 2048

typedef float f32x4 __attribute__((ext_vector_type(4)));
typedef __bf16 bf16x8 __attribute__((ext_vector_type(8)));
typedef unsigned int u32;
typedef const __attribute__((address_space(1))) u32* gptr_t;
typedef __attribute__((address_space(3))) u32* lptr_t;

__device__ __forceinline__ void gload_lds16(const void* g, void* l) {
    __builtin_amdgcn_global_load_lds((gptr_t)g, (lptr_t)l, 16, 0, 0);
}

// ---- per-wire constants K1,K2 from params[8,3] ----
__global__ void k_prep(const float* __restrict__ params, float* __restrict__ Kc) {
    int i = threadIdx.x;
    if (i < 8) {
        float a = params[i*3+0], b = params[i*3+1], g = params[i*3+2];
        float sa, ca, sb, cb, sg, cg;
        sincosf(a, &sa, &ca);
        sincosf(b, &sb, &cb);
        sincosf(g, &sg, &cg);
        Kc[i]   = sa*sb*sg + ca*cg;   // K1
        Kc[8+i] = cb*sg;              // K2
    }
}

// ---- W2 fp32 -> bf16 ----
__global__ __launch_bounds__(256) void k_w2(const float* __restrict__ W2,
                                            __hip_bfloat16* __restrict__ W2b) {
    int i = (blockIdx.x * 256 + threadIdx.x) * 4;
    float4 v = *(const float4*)(W2 + i);
    __hip_bfloat16 o[4];
    o[0] = __float2bfloat16(v.x); o[1] = __float2bfloat16(v.y);
    o[2] = __float2bfloat16(v.z); o[3] = __float2bfloat16(v.w);
    *(ulong1*)(W2b + i) = *(ulong1*)o;
}

// ---- ev[n][8]: closed-form PauliZ expvals ----
__global__ __launch_bounds__(256) void k_ev(const float* __restrict__ x,
                                            const float* __restrict__ Kc,
                                            float* __restrict__ ev) {
    int n = blockIdx.x * 256 + threadIdx.x;
    float4 x0 = *(const float4*)(x + (size_t)n*8);
    float4 x1 = *(const float4*)(x + (size_t)n*8 + 4);
    float xs[8] = {x0.x, x0.y, x0.z, x0.w, x1.x, x1.y, x1.z, x1.w};
    float z[8];
    #pragma unroll
    for (int i = 0; i < 8; i++) {
        float s, c;
        __sincosf(xs[i], &s, &c);
        z[i] = c * Kc[i] - s * Kc[8+i];
    }
    float evv[8];
    float p = z[0];
    #pragma unroll
    for (int j = 1; j < 8; j++) { p *= z[j]; evv[j] = p; }
    float sfx = z[7];
    #pragma unroll
    for (int j = 6; j >= 1; j--) sfx *= z[j];
    evv[0] = sfx;
    *(float4*)(ev + (size_t)n*8)     = make_float4(evv[0], evv[1], evv[2], evv[3]);
    *(float4*)(ev + (size_t)n*8 + 4) = make_float4(evv[4], evv[5], evv[6], evv[7]);
}

// ---- h = relu(ev @ W1^T + b1), bf16 [NS, FFN]; one block per sample ----
__global__ __launch_bounds__(256) void k_h(const float* __restrict__ ev,
                                           const float* __restrict__ W1,
                                           const float* __restrict__ b1,
                                           __hip_bfloat16* __restrict__ h) {
    int n = blockIdx.x;
    int t = threadIdx.x;
    float e[8];
    #pragma unroll
    for (int i = 0; i < 8; i++) e[i] = ev[(size_t)n*8 + i];
    int f0 = t * 8;
    const float* w = W1 + (size_t)f0 * 8;
    bf16x8 hv;
    #pragma unroll
    for (int r = 0; r < 8; r++) {
        float acc = b1[f0 + r];
        #pragma unroll
        for (int i = 0; i < 8; i++) acc += e[i] * w[r*8 + i];
        acc = fmaxf(acc, 0.f);
        hv[r] = (__bf16)acc;
    }
    *(bf16x8*)(h + (size_t)n * FFN + f0) = hv;
}

// ---- GEMM2: C[M,512] = A[M,2048](bf16) * W2b[512,2048]^T + b2, fp32 out ----
#define BM 128
#define BN 128
#define BK 32

__global__ __launch_bounds__(256) void k_gemm(
        const __hip_bfloat16* __restrict__ A,   // h  [NS, KDIM]
        const __hip_bfloat16* __restrict__ B,   // W2b [EMB, KDIM]
        const float* __restrict__ b2,
        float* __restrict__ C) {
    __shared__ __hip_bfloat16 As[BM * BK];
    __shared__ __hip_bfloat16 Bs[BN * BK];
    int tid  = threadIdx.x;
    int wave = tid >> 6, lane = tid & 63;
    int bx = blockIdx.x;
    int bm = bx >> 2, bn = bx & 3;      // bn fastest: A-sharing blocks adjacent
    int wm = wave >> 1, wn = wave & 1;

    // staging: wave stages rows [wave*32, wave*32+32) of both tiles, 2 chunks of 16 rows
    int srow  = wave * 32 + (lane >> 2);
    int skoff = (lane & 3) * 8;
    const __hip_bfloat16* gA = A + (size_t)(bm*BM + srow) * KDIM + skoff;
    const __hip_bfloat16* gB = B + (size_t)(bn*BN + srow) * KDIM + skoff;

    f32x4 acc[4][4] = {};
    int quad = lane >> 4, l16 = lane & 15;

    for (int k0 = 0; k0 < KDIM; k0 += BK) {
        gload_lds16(gA,           &As[(wave*32) * BK]);
        gload_lds16(gA + 16*KDIM, &As[(wave*32 + 16) * BK]);
        gload_lds16(gB,           &Bs[(wave*32) * BK]);
        gload_lds16(gB + 16*KDIM, &Bs[(wave*32 + 16) * BK]);
        gA += BK; gB += BK;
        __syncthreads();
        bf16x8 af[4], bf[4];
        #pragma unroll
        for (int mi = 0; mi < 4; mi++)
            af[mi] = *(const bf16x8*)&As[(wm*64 + mi*16 + l16) * BK + quad*8];
        #pragma unroll
        for (int ni = 0; ni < 4; ni++)
            bf[ni] = *(const bf16x8*)&Bs[(wn*64 + ni*16 + l16) * BK + quad*8];
        #pragma unroll
        for (int mi = 0; mi < 4; mi++)
            #pragma unroll
            for (int ni = 0; ni < 4; ni++)
                acc[mi][ni] = __builtin_amdgcn_mfma_f32_16x16x32_bf16(
                                  af[mi], bf[ni], acc[mi][ni], 0, 0, 0);
        __syncthreads();
    }

    #pragma unroll
    for (int ni = 0; ni < 4; ni++) {
        int col = bn*BN + wn*64 + ni*16 + l16;
        float bias = b2[col];
        #pragma unroll
        for (int mi = 0; mi < 4; mi++) {
            int row = bm*BM + wm*64 + mi*16 + quad*4;
            #pragma unroll
            for (int r = 0; r < 4; r++)
                C[(size_t)(row + r) * EMB + col] = acc[mi][ni][r] + bias;
        }
    }
}

extern "C" void kernel_launch(void* const* d_in, const int* in_sizes, int n_in,
                              void* d_out, int out_size, void* d_ws, size_t ws_size,
                              hipStream_t stream) {
    const float* x      = (const float*)d_in[0];  // [16,2048,8]
    const float* params = (const float*)d_in[1];  // [8,3]
    const float* W1     = (const float*)d_in[2];  // [2048,8]
    const float* b1     = (const float*)d_in[3];  // [2048]
    const float* W2     = (const float*)d_in[4];  // [512,2048]
    const float* b2     = (const float*)d_in[5];  // [512]
    float* out = (float*)d_out;                   // [32768,512]

    char* ws = (char*)d_ws;
    __hip_bfloat16* W2b = (__hip_bfloat16*)ws;                              // 2 MB
    float* Kc = (float*)(ws + 2*1024*1024);                                 // 64 B
    float* ev = (float*)(ws + 2*1024*1024 + 256);                           // 1 MB
    __hip_bfloat16* h = (__hip_bfloat16*)(ws + 2*1024*1024 + 256 + NS*8*4); // 128 MB

    k_prep<<<1, 64, 0, stream>>>(params, Kc);
    k_w2<<<(EMB*KDIM)/(256*4), 256, 0, stream>>>(W2, W2b);
    k_ev<<<NS/256, 256, 0, stream>>>(x, Kc, ev);
    k_h<<<NS, 256, 0, stream>>>(ev, W1, b1, h);
    k_gemm<<<(NS/BM) * (EMB/BN), 256, 0, stream>>>(h, W2b, b2, out);
}

// Round 2
// 225.094 us; speedup vs baseline: 1.9153x; 1.9153x over previous
//
#include <hip/hip_runtime.h>
#include <hip/hip_bf16.h>

#define NS 32768          // B*S samples
#define FFN 2048
#define EMB 512
#define KDIM 2048

typedef float f32x4 __attribute__((ext_vector_type(4)));
typedef __bf16 bf16x8 __attribute__((ext_vector_type(8)));
typedef unsigned int u32;
typedef const __attribute__((address_space(1))) u32* gptr_t;
typedef __attribute__((address_space(3))) u32* lptr_t;

__device__ __forceinline__ void gload_lds16(const void* g, void* l) {
    __builtin_amdgcn_global_load_lds((gptr_t)g, (lptr_t)l, 16, 0, 0);
}

// ---- per-wire constants K1,K2 from params[8,3] ----
__global__ void k_prep(const float* __restrict__ params, float* __restrict__ Kc) {
    int i = threadIdx.x;
    if (i < 8) {
        float a = params[i*3+0], b = params[i*3+1], g = params[i*3+2];
        float sa, ca, sb, cb, sg, cg;
        sincosf(a, &sa, &ca);
        sincosf(b, &sb, &cb);
        sincosf(g, &sg, &cg);
        Kc[i]   = sa*sb*sg + ca*cg;   // K1
        Kc[8+i] = cb*sg;              // K2
    }
}

// ---- W2 fp32 -> bf16 ----
__global__ __launch_bounds__(256) void k_w2(const float* __restrict__ W2,
                                            __hip_bfloat16* __restrict__ W2b) {
    int i = (blockIdx.x * 256 + threadIdx.x) * 4;
    float4 v = *(const float4*)(W2 + i);
    __hip_bfloat16 o[4];
    o[0] = __float2bfloat16(v.x); o[1] = __float2bfloat16(v.y);
    o[2] = __float2bfloat16(v.z); o[3] = __float2bfloat16(v.w);
    *(ulong1*)(W2b + i) = *(ulong1*)o;
}

// ---- ev[n][8]: closed-form PauliZ expvals ----
__global__ __launch_bounds__(256) void k_ev(const float* __restrict__ x,
                                            const float* __restrict__ Kc,
                                            float* __restrict__ ev) {
    int n = blockIdx.x * 256 + threadIdx.x;
    float4 x0 = *(const float4*)(x + (size_t)n*8);
    float4 x1 = *(const float4*)(x + (size_t)n*8 + 4);
    float xs[8] = {x0.x, x0.y, x0.z, x0.w, x1.x, x1.y, x1.z, x1.w};
    float z[8];
    #pragma unroll
    for (int i = 0; i < 8; i++) {
        float s, c;
        __sincosf(xs[i], &s, &c);
        z[i] = c * Kc[i] - s * Kc[8+i];
    }
    float evv[8];
    float p = z[0];
    #pragma unroll
    for (int j = 1; j < 8; j++) { p *= z[j]; evv[j] = p; }
    float sfx = z[7];
    #pragma unroll
    for (int j = 6; j >= 1; j--) sfx *= z[j];
    evv[0] = sfx;
    *(float4*)(ev + (size_t)n*8)     = make_float4(evv[0], evv[1], evv[2], evv[3]);
    *(float4*)(ev + (size_t)n*8 + 4) = make_float4(evv[4], evv[5], evv[6], evv[7]);
}

// ---- h = relu(ev @ W1^T + b1), bf16 [NS, FFN] ----
// R1 fix: W1 rows for thread t live in registers for the whole block
// (loaded once, coalesced float4), loop over KH_SPB samples. R0 version
// re-issued 64 stride-64 scalar W1 loads per sample -> 515 GB/s, 260 us.
#define KH_BLOCKS 1024
#define KH_SPB (NS / KH_BLOCKS)   // 32 samples per block

__global__ __launch_bounds__(256) void k_h(const float* __restrict__ ev,
                                           const float* __restrict__ W1,
                                           const float* __restrict__ b1,
                                           __hip_bfloat16* __restrict__ h) {
    int t = threadIdx.x;
    int f0 = t * 8;
    float w[8][8];
    #pragma unroll
    for (int r = 0; r < 8; r++) {
        float4 a = *(const float4*)(W1 + (size_t)(f0 + r) * 8);
        float4 b = *(const float4*)(W1 + (size_t)(f0 + r) * 8 + 4);
        w[r][0] = a.x; w[r][1] = a.y; w[r][2] = a.z; w[r][3] = a.w;
        w[r][4] = b.x; w[r][5] = b.y; w[r][6] = b.z; w[r][7] = b.w;
    }
    float bias[8];
    #pragma unroll
    for (int r = 0; r < 8; r++) bias[r] = b1[f0 + r];

    int n0 = blockIdx.x * KH_SPB;
    for (int s = 0; s < KH_SPB; s++) {
        int n = n0 + s;
        float e[8];
        #pragma unroll
        for (int i = 0; i < 8; i++) e[i] = ev[(size_t)n * 8 + i];  // wave-uniform -> broadcast
        bf16x8 hv;
        #pragma unroll
        for (int r = 0; r < 8; r++) {
            float acc = bias[r];
            #pragma unroll
            for (int i = 0; i < 8; i++) acc += e[i] * w[r][i];
            hv[r] = (__bf16)fmaxf(acc, 0.f);
        }
        *(bf16x8*)(h + (size_t)n * FFN + f0) = hv;   // 256 threads x 16B contiguous
    }
}

// ---- GEMM2: C[M,512] = A[M,2048](bf16) * W2b[512,2048]^T + b2, fp32 out ----
#define BM 128
#define BN 128
#define BK 32

__global__ __launch_bounds__(256) void k_gemm(
        const __hip_bfloat16* __restrict__ A,   // h  [NS, KDIM]
        const __hip_bfloat16* __restrict__ B,   // W2b [EMB, KDIM]
        const float* __restrict__ b2,
        float* __restrict__ C) {
    __shared__ __hip_bfloat16 As[BM * BK];
    __shared__ __hip_bfloat16 Bs[BN * BK];
    int tid  = threadIdx.x;
    int wave = tid >> 6, lane = tid & 63;
    int bx = blockIdx.x;
    int bm = bx >> 2, bn = bx & 3;      // bn fastest: A-sharing blocks adjacent
    int wm = wave >> 1, wn = wave & 1;

    // staging: wave stages rows [wave*32, wave*32+32) of both tiles, 2 chunks of 16 rows
    int srow  = wave * 32 + (lane >> 2);
    int skoff = (lane & 3) * 8;
    const __hip_bfloat16* gA = A + (size_t)(bm*BM + srow) * KDIM + skoff;
    const __hip_bfloat16* gB = B + (size_t)(bn*BN + srow) * KDIM + skoff;

    f32x4 acc[4][4] = {};
    int quad = lane >> 4, l16 = lane & 15;

    for (int k0 = 0; k0 < KDIM; k0 += BK) {
        gload_lds16(gA,           &As[(wave*32) * BK]);
        gload_lds16(gA + 16*KDIM, &As[(wave*32 + 16) * BK]);
        gload_lds16(gB,           &Bs[(wave*32) * BK]);
        gload_lds16(gB + 16*KDIM, &Bs[(wave*32 + 16) * BK]);
        gA += BK; gB += BK;
        __syncthreads();
        bf16x8 af[4], bf[4];
        #pragma unroll
        for (int mi = 0; mi < 4; mi++)
            af[mi] = *(const bf16x8*)&As[(wm*64 + mi*16 + l16) * BK + quad*8];
        #pragma unroll
        for (int ni = 0; ni < 4; ni++)
            bf[ni] = *(const bf16x8*)&Bs[(wn*64 + ni*16 + l16) * BK + quad*8];
        #pragma unroll
        for (int mi = 0; mi < 4; mi++)
            #pragma unroll
            for (int ni = 0; ni < 4; ni++)
                acc[mi][ni] = __builtin_amdgcn_mfma_f32_16x16x32_bf16(
                                  af[mi], bf[ni], acc[mi][ni], 0, 0, 0);
        __syncthreads();
    }

    #pragma unroll
    for (int ni = 0; ni < 4; ni++) {
        int col = bn*BN + wn*64 + ni*16 + l16;
        float bias = b2[col];
        #pragma unroll
        for (int mi = 0; mi < 4; mi++) {
            int row = bm*BM + wm*64 + mi*16 + quad*4;
            #pragma unroll
            for (int r = 0; r < 4; r++)
                C[(size_t)(row + r) * EMB + col] = acc[mi][ni][r] + bias;
        }
    }
}

extern "C" void kernel_launch(void* const* d_in, const int* in_sizes, int n_in,
                              void* d_out, int out_size, void* d_ws, size_t ws_size,
                              hipStream_t stream) {
    const float* x      = (const float*)d_in[0];  // [16,2048,8]
    const float* params = (const float*)d_in[1];  // [8,3]
    const float* W1     = (const float*)d_in[2];  // [2048,8]
    const float* b1     = (const float*)d_in[3];  // [2048]
    const float* W2     = (const float*)d_in[4];  // [512,2048]
    const float* b2     = (const float*)d_in[5];  // [512]
    float* out = (float*)d_out;                   // [32768,512]

    char* ws = (char*)d_ws;
    __hip_bfloat16* W2b = (__hip_bfloat16*)ws;                              // 2 MB
    float* Kc = (float*)(ws + 2*1024*1024);                                 // 64 B
    float* ev = (float*)(ws + 2*1024*1024 + 256);                           // 1 MB
    __hip_bfloat16* h = (__hip_bfloat16*)(ws + 2*1024*1024 + 256 + NS*8*4); // 128 MB

    k_prep<<<1, 64, 0, stream>>>(params, Kc);
    k_w2<<<(EMB*KDIM)/(256*4), 256, 0, stream>>>(W2, W2b);
    k_ev<<<NS/256, 256, 0, stream>>>(x, Kc, ev);
    k_h<<<KH_BLOCKS, 256, 0, stream>>>(ev, W1, b1, h);
    k_gemm<<<(NS/BM) * (EMB/BN), 256, 0, stream>>>(h, W2b, b2, out);
}

// Round 3
// 185.768 us; speedup vs baseline: 2.3208x; 1.2117x over previous
//
#include <hip/hip_runtime.h>
#include <hip/hip_bf16.h>

#define NS 32768          // B*S samples
#define FFN 2048          // = KDIM of GEMM2
#define EMB 512
#define KDIM 2048

typedef float f32x4 __attribute__((ext_vector_type(4)));
typedef __bf16 bf16x8 __attribute__((ext_vector_type(8)));
typedef __bf16 bf16x2 __attribute__((ext_vector_type(2)));
typedef unsigned int u32;
typedef const __attribute__((address_space(1))) u32* gptr_t;
typedef __attribute__((address_space(3))) u32* lptr_t;

#if __has_builtin(__builtin_amdgcn_fdot2_f32_bf16)
#define HAS_FDOT2 1
#else
#define HAS_FDOT2 0
#endif

__device__ __forceinline__ void gload_lds16(const void* g, void* l) {
    __builtin_amdgcn_global_load_lds((gptr_t)g, (lptr_t)l, 16, 0, 0);
}

// ---- per-wire constants K1,K2 from params[8,3] ----
__global__ void k_prep(const float* __restrict__ params, float* __restrict__ Kc) {
    int i = threadIdx.x;
    if (i < 8) {
        float a = params[i*3+0], b = params[i*3+1], g = params[i*3+2];
        float sa, ca, sb, cb, sg, cg;
        sincosf(a, &sa, &ca);
        sincosf(b, &sb, &cb);
        sincosf(g, &sg, &cg);
        Kc[i]   = sa*sb*sg + ca*cg;   // K1
        Kc[8+i] = cb*sg;              // K2
    }
}

// ---- convert W2 -> bf16; blocks 0..15 also convert W1, block 16 converts b1 ----
__global__ __launch_bounds__(256) void k_w2(const float* __restrict__ W2,
                                            const float* __restrict__ W1,
                                            const float* __restrict__ b1,
                                            __hip_bfloat16* __restrict__ W2b,
                                            __hip_bfloat16* __restrict__ W1bg,
                                            __hip_bfloat16* __restrict__ b1bg) {
    int t = threadIdx.x;
    int i = (blockIdx.x * 256 + t) * 4;
    float4 v = *(const float4*)(W2 + i);
    __hip_bfloat16 o[4];
    o[0] = __float2bfloat16(v.x); o[1] = __float2bfloat16(v.y);
    o[2] = __float2bfloat16(v.z); o[3] = __float2bfloat16(v.w);
    *(ulong1*)(W2b + i) = *(ulong1*)o;
    if (blockIdx.x < 16) {           // W1: 16384 elems / 16 blocks = 1024/block
        int j = blockIdx.x * 1024 + t * 4;
        float4 w = *(const float4*)(W1 + j);
        __hip_bfloat16 p[4];
        p[0] = __float2bfloat16(w.x); p[1] = __float2bfloat16(w.y);
        p[2] = __float2bfloat16(w.z); p[3] = __float2bfloat16(w.w);
        *(ulong1*)(W1bg + j) = *(ulong1*)p;
    } else if (blockIdx.x == 16) {   // b1: 2048 elems, 8/thread
        int j = t * 8;
        #pragma unroll
        for (int r = 0; r < 8; r++) b1bg[j+r] = __float2bfloat16(b1[j+r]);
    }
}

// ---- evb[n][8] bf16: closed-form PauliZ expvals ----
__global__ __launch_bounds__(256) void k_ev(const float* __restrict__ x,
                                            const float* __restrict__ Kc,
                                            __hip_bfloat16* __restrict__ evb) {
    int n = blockIdx.x * 256 + threadIdx.x;
    float4 x0 = *(const float4*)(x + (size_t)n*8);
    float4 x1 = *(const float4*)(x + (size_t)n*8 + 4);
    float xs[8] = {x0.x, x0.y, x0.z, x0.w, x1.x, x1.y, x1.z, x1.w};
    float z[8];
    #pragma unroll
    for (int i = 0; i < 8; i++) {
        float s, c;
        __sincosf(xs[i], &s, &c);
        z[i] = c * Kc[i] - s * Kc[8+i];
    }
    float evv[8];
    float p = z[0];
    #pragma unroll
    for (int j = 1; j < 8; j++) { p *= z[j]; evv[j] = p; }
    float sfx = z[7];
    #pragma unroll
    for (int j = 6; j >= 1; j--) sfx *= z[j];
    evv[0] = sfx;
    __hip_bfloat16 o[8];
    #pragma unroll
    for (int i = 0; i < 8; i++) o[i] = __float2bfloat16(evv[i]);
    *(bf16x8*)(evb + (size_t)n*8) = *(bf16x8*)o;
}

// ---- fused: C[M,512] = relu(ev@W1^T + b1) @ W2b^T + b2 ----
// h is never materialized: A-fragments generated in registers from ev (regs,
// bf16) x W1 (LDS, bank-swizzled). Wave owns 32 rows x 128 cols.
#define BM 128
#define BN 128
#define BK 32

__global__ __launch_bounds__(256, 3) void k_gemm(
        const __hip_bfloat16* __restrict__ evb,   // [NS, 8]
        const __hip_bfloat16* __restrict__ W1bg,  // [2048, 8]
        const __hip_bfloat16* __restrict__ b1bg,  // [2048]
        const __hip_bfloat16* __restrict__ W2b,   // [512, 2048]
        const float* __restrict__ b2,
        float* __restrict__ C) {
    __shared__ __hip_bfloat16 Bs[BN * BK];      // 8 KB, XOR chunk-swizzled
    __shared__ __hip_bfloat16 W1s[2304 * 8];    // 36 KB, row k at slot k+(k>>3)
    __shared__ __hip_bfloat16 b1s[2048];        // 4 KB

    int tid = threadIdx.x, wave = tid >> 6, lane = tid & 63;
    int quad = lane >> 4, l16 = lane & 15;
    int bx = blockIdx.x, bm = bx >> 2, bn = bx & 3;

    // one-time: W1bg -> W1s (swizzled: quads hit disjoint bank groups), b1 -> b1s
    {
        const bf16x8* src = (const bf16x8*)(W1bg + (size_t)tid * 64);
        #pragma unroll
        for (int r = 0; r < 8; r++)
            *(bf16x8*)&W1s[(tid * 9 + r) * 8] = src[r];   // slot = k + (k>>3), k = tid*8+r
        *(bf16x8*)&b1s[tid * 8] = *(const bf16x8*)(b1bg + tid * 8);
    }

    // ev rows for this thread's two m-tiles (registers for whole K-loop)
    bf16x8 evr[2];
    #pragma unroll
    for (int m = 0; m < 2; m++)
        evr[m] = *(const bf16x8*)(evb + (size_t)(bm*BM + wave*32 + m*16 + l16) * 8);
#if HAS_FDOT2
    bf16x2 ep[2][4];
    #pragma unroll
    for (int m = 0; m < 2; m++)
        #pragma unroll
        for (int p = 0; p < 4; p++)
            ep[m][p] = __builtin_shufflevector(evr[m], evr[m], 0, 0), // placeholder init
            ep[m][p] = (bf16x2){evr[m][2*p], evr[m][2*p+1]};
#else
    float ef[2][8];
    #pragma unroll
    for (int m = 0; m < 2; m++)
        #pragma unroll
        for (int i = 0; i < 8; i++) ef[m][i] = (float)evr[m][i];
#endif

    // B staging (global_load_lds, XOR chunk swizzle: slot c holds chunk c^f(row))
    int srow = lane >> 2;                 // row within 16-row chunk
    int q_st = (lane & 3) ^ ((lane >> 3) & 3);
    const __hip_bfloat16* gB = W2b + (size_t)(bn*BN + wave*32 + srow) * KDIM + q_st * 8;
    int rdsw = (quad ^ ((l16 >> 1) & 3)) * 8;   // reader's swizzled half-offset

    f32x4 acc[2][8] = {};

    for (int k0 = 0; k0 < KDIM; k0 += BK) {
        gload_lds16(gB,            &Bs[(wave*32) * BK]);
        gload_lds16(gB + 16*KDIM,  &Bs[(wave*32 + 16) * BK]);
        gB += BK;
        __syncthreads();   // also covers one-time W1s/b1s staging on iter 0

        // generate A-fragments: af[m][kk] = relu(b1[k] + dot8(ev[row], W1[k]))
        bf16x8 af[2];
        int kb = k0 + quad * 8;
        int wbase = (kb + (kb >> 3)) * 8;   // swizzled W1s half-offset, kk-contiguous
        #pragma unroll
        for (int kk = 0; kk < 8; kk++) {
            bf16x8 w = *(const bf16x8*)&W1s[wbase + kk * 8];
            float b1v = (float)b1s[kb + kk];
            #pragma unroll
            for (int m = 0; m < 2; m++) {
                float a = b1v;
#if HAS_FDOT2
                #pragma unroll
                for (int p = 0; p < 4; p++) {
                    bf16x2 wp = (bf16x2){w[2*p], w[2*p+1]};
                    a = __builtin_amdgcn_fdot2_f32_bf16(ep[m][p], wp, a, false);
                }
#else
                #pragma unroll
                for (int i = 0; i < 8; i++) a = fmaf(ef[m][i], (float)w[i], a);
#endif
                af[m][kk] = (__bf16)fmaxf(a, 0.f);
            }
        }

        bf16x8 bf[8];
        #pragma unroll
        for (int ni = 0; ni < 8; ni++)
            bf[ni] = *(const bf16x8*)&Bs[(ni*16 + l16) * BK + rdsw];

        #pragma unroll
        for (int m = 0; m < 2; m++)
            #pragma unroll
            for (int ni = 0; ni < 8; ni++)
                acc[m][ni] = __builtin_amdgcn_mfma_f32_16x16x32_bf16(
                                 af[m], bf[ni], acc[m][ni], 0, 0, 0);
        __syncthreads();
    }

    #pragma unroll
    for (int ni = 0; ni < 8; ni++) {
        int col = bn*BN + ni*16 + l16;
        float bias = b2[col];
        #pragma unroll
        for (int m = 0; m < 2; m++) {
            int row = bm*BM + wave*32 + m*16 + quad*4;
            #pragma unroll
            for (int r = 0; r < 4; r++)
                C[(size_t)(row + r) * EMB + col] = acc[m][ni][r] + bias;
        }
    }
}

extern "C" void kernel_launch(void* const* d_in, const int* in_sizes, int n_in,
                              void* d_out, int out_size, void* d_ws, size_t ws_size,
                              hipStream_t stream) {
    const float* x      = (const float*)d_in[0];  // [16,2048,8]
    const float* params = (const float*)d_in[1];  // [8,3]
    const float* W1     = (const float*)d_in[2];  // [2048,8]
    const float* b1     = (const float*)d_in[3];  // [2048]
    const float* W2     = (const float*)d_in[4];  // [512,2048]
    const float* b2     = (const float*)d_in[5];  // [512]
    float* out = (float*)d_out;                   // [32768,512]

    char* ws = (char*)d_ws;
    __hip_bfloat16* W2b  = (__hip_bfloat16*)ws;                    // 2 MB
    __hip_bfloat16* W1bg = (__hip_bfloat16*)(ws + 2097152);        // 32 KB
    __hip_bfloat16* b1bg = (__hip_bfloat16*)(ws + 2097152+32768);  // 4 KB
    float*          Kc   = (float*)(ws + 2097152+32768+4096);      // 256 B
    __hip_bfloat16* evb  = (__hip_bfloat16*)(ws + 2097152+32768+4096+256); // 512 KB

    k_prep<<<1, 64, 0, stream>>>(params, Kc);
    k_w2<<<(EMB*KDIM)/(256*4), 256, 0, stream>>>(W2, W1, b1, W2b, W1bg, b1bg);
    k_ev<<<NS/256, 256, 0, stream>>>(x, Kc, evb);
    k_gemm<<<(NS/BM) * (EMB/BN), 256, 0, stream>>>(evb, W1bg, b1bg, W2b, b2, out);
}

// Round 4
// 177.558 us; speedup vs baseline: 2.4281x; 1.0462x over previous
//
#include <hip/hip_runtime.h>
#include <hip/hip_bf16.h>

#define NS 32768          // B*S samples
#define EMB 512
#define KDIM 2048

typedef float f32x16 __attribute__((ext_vector_type(16)));
typedef __bf16 bf16x8 __attribute__((ext_vector_type(8)));
typedef __bf16 bf16x2 __attribute__((ext_vector_type(2)));
typedef unsigned int u32;
typedef const __attribute__((address_space(1))) u32* gptr_t;
typedef __attribute__((address_space(3))) u32* lptr_t;

#if __has_builtin(__builtin_amdgcn_fdot2_f32_bf16)
#define HAS_FDOT2 1
#else
#define HAS_FDOT2 0
#endif

__device__ __forceinline__ void gload_lds16(const void* g, void* l) {
    __builtin_amdgcn_global_load_lds((gptr_t)g, (lptr_t)l, 16, 0, 0);
}

// ---- prep: W2 -> bf16 (1024 blocks); W1 -> bf16 (16 blocks) ----
__global__ __launch_bounds__(256) void k_prep(const float* __restrict__ W2,
                                              const float* __restrict__ W1,
                                              __hip_bfloat16* __restrict__ W2b,
                                              __hip_bfloat16* __restrict__ W1bg) {
    int t = threadIdx.x;
    if (blockIdx.x < 1024) {
        int i = (blockIdx.x * 256 + t) * 4;
        float4 v = *(const float4*)(W2 + i);
        __hip_bfloat16 o[4];
        o[0] = __float2bfloat16(v.x); o[1] = __float2bfloat16(v.y);
        o[2] = __float2bfloat16(v.z); o[3] = __float2bfloat16(v.w);
        *(ulong1*)(W2b + i) = *(ulong1*)o;
    } else {
        int j = (blockIdx.x - 1024) * 1024 + t * 4;   // 16 blocks x 1024
        float4 w = *(const float4*)(W1 + j);
        __hip_bfloat16 p[4];
        p[0] = __float2bfloat16(w.x); p[1] = __float2bfloat16(w.y);
        p[2] = __float2bfloat16(w.z); p[3] = __float2bfloat16(w.w);
        *(ulong1*)(W1bg + j) = *(ulong1*)p;
    }
}

// ---- fused: C[128,256-tile] = relu(ev @ W1^T + b1) @ W2b^T + b2 ----
// ev computed inline (closed-form circuit). A generated in registers.
// B staged in 32x32x16 MFMA fragment order via per-lane global_load_lds:
// frag f (ni=f>>1, t=f&1) occupies Bs[f*512 .. +512], lane l's 8 bf16 at
// Bs[f*512 + l*8]  ->  reads are base+lane*16B, imm offset, conflict-free.
#define BM 128
#define BN 256

__global__ __launch_bounds__(256, 2) void k_gemm(
        const float* __restrict__ x,       // [NS, 8]
        const float* __restrict__ params,  // [8, 3]
        const __hip_bfloat16* __restrict__ W1bg,  // [2048, 8] bf16
        const float* __restrict__ b1,      // [2048]
        const __hip_bfloat16* __restrict__ W2b,   // [512, 2048] bf16
        const float* __restrict__ b2,      // [512]
        float* __restrict__ C) {           // [NS, 512]
    __shared__ __hip_bfloat16 Bs[16 * 512];   // 16 frags x 1KB = 16 KB
    __shared__ __hip_bfloat16 W1s[KDIM * 8];  // 32 KB
    __shared__ float b1s[KDIM];               // 8 KB
    __shared__ __hip_bfloat16 evs[BM * 8];    // 2 KB

    int tid = threadIdx.x, wave = tid >> 6, lane = tid & 63;
    int l31 = lane & 31, half = lane >> 5;
    int bx = blockIdx.x, bm = bx >> 1, bn = bx & 1;

    // --- inline ev for this block's 128 rows (threads 0..127, 1 sample each)
    if (tid < 128) {
        float K1[8], K2[8];
        #pragma unroll
        for (int i = 0; i < 8; i++) {
            float a = params[i*3+0], b = params[i*3+1], g = params[i*3+2];
            float sa, ca, sb, cb, sg, cg;
            __sincosf(a, &sa, &ca);
            __sincosf(b, &sb, &cb);
            __sincosf(g, &sg, &cg);
            K1[i] = sa*sb*sg + ca*cg;
            K2[i] = cb*sg;
        }
        int n = bm * BM + tid;
        float4 x0 = *(const float4*)(x + (size_t)n*8);
        float4 x1 = *(const float4*)(x + (size_t)n*8 + 4);
        float xs[8] = {x0.x, x0.y, x0.z, x0.w, x1.x, x1.y, x1.z, x1.w};
        float z[8];
        #pragma unroll
        for (int i = 0; i < 8; i++) {
            float s, c;
            __sincosf(xs[i], &s, &c);
            z[i] = c * K1[i] - s * K2[i];
        }
        float evv[8];
        float p = z[0];
        #pragma unroll
        for (int j = 1; j < 8; j++) { p *= z[j]; evv[j] = p; }
        float sfx = z[7];
        #pragma unroll
        for (int j = 6; j >= 1; j--) sfx *= z[j];
        evv[0] = sfx;
        __hip_bfloat16 o[8];
        #pragma unroll
        for (int i = 0; i < 8; i++) o[i] = __float2bfloat16(evv[i]);
        *(bf16x8*)&evs[tid * 8] = *(bf16x8*)o;
    }
    // --- stage W1 (bf16) + b1 (f32) into LDS
    for (int i = tid; i < KDIM; i += 256) {
        *(bf16x8*)&W1s[i * 8] = *(const bf16x8*)(W1bg + (size_t)i * 8);
        b1s[i] = b1[i];
    }
    __syncthreads();

    // this thread's ev row (row = wave*32 + l31), as 4 packed bf16x2 pairs
    bf16x8 evr = *(const bf16x8*)&evs[(wave * 32 + l31) * 8];
#if HAS_FDOT2
    bf16x2 ep[4];
    #pragma unroll
    for (int p = 0; p < 4; p++) ep[p] = (bf16x2){evr[2*p], evr[2*p+1]};
#else
    float ef[8];
    #pragma unroll
    for (int i = 0; i < 8; i++) ef[i] = (float)evr[i];
#endif

    // B staging pointers: wave stages frags f = wave*4 .. wave*4+3
    const __hip_bfloat16* gBp[4];
    #pragma unroll
    for (int i = 0; i < 4; i++) {
        int f = wave * 4 + i, ni = f >> 1, t = f & 1;
        gBp[i] = W2b + (size_t)(bn*BN + ni*32 + l31) * KDIM + t*16 + half*8;
    }

    f32x16 acc[8] = {};

    for (int k0 = 0; k0 < KDIM; k0 += 32) {
        #pragma unroll
        for (int i = 0; i < 4; i++) {
            gload_lds16(gBp[i], &Bs[(wave*4 + i) * 512]);
            gBp[i] += 32;
        }
        __syncthreads();

        #pragma unroll
        for (int t = 0; t < 2; t++) {
            int kb = k0 + t*16 + half*8;
            // A-fragment: af[j] = relu(b1[kb+j] + dot8(ev_row, W1[kb+j]))
            float4 ba = *(const float4*)&b1s[kb];
            float4 bb = *(const float4*)&b1s[kb + 4];
            float bv[8] = {ba.x, ba.y, ba.z, ba.w, bb.x, bb.y, bb.z, bb.w};
            bf16x8 af;
            #pragma unroll
            for (int j = 0; j < 8; j++) {
                bf16x8 w = *(const bf16x8*)&W1s[(kb + j) * 8];
                float a = bv[j];
#if HAS_FDOT2
                #pragma unroll
                for (int p = 0; p < 4; p++) {
                    bf16x2 wp = (bf16x2){w[2*p], w[2*p+1]};
                    a = __builtin_amdgcn_fdot2_f32_bf16(ep[p], wp, a, false);
                }
#else
                #pragma unroll
                for (int i = 0; i < 8; i++) a = fmaf(ef[i], (float)w[i], a);
#endif
                af[j] = (__bf16)fmaxf(a, 0.f);
            }
            #pragma unroll
            for (int ni = 0; ni < 8; ni++) {
                bf16x8 bfr = *(const bf16x8*)&Bs[(ni*2 + t) * 512 + lane * 8];
                acc[ni] = __builtin_amdgcn_mfma_f32_32x32x16_bf16(
                              af, bfr, acc[ni], 0, 0, 0);
            }
        }
        __syncthreads();
    }

    // epilogue: 32x32 C/D layout: col = lane&31, row = (r&3)+8*(r>>2)+4*half
    int rbase = bm*BM + wave*32 + 4*half;
    #pragma unroll
    for (int ni = 0; ni < 8; ni++) {
        int col = bn*BN + ni*32 + l31;
        float bias = b2[col];
        #pragma unroll
        for (int r = 0; r < 16; r++) {
            int row = rbase + (r & 3) + 8 * (r >> 2);
            C[(size_t)row * EMB + col] = acc[ni][r] + bias;
        }
    }
}

extern "C" void kernel_launch(void* const* d_in, const int* in_sizes, int n_in,
                              void* d_out, int out_size, void* d_ws, size_t ws_size,
                              hipStream_t stream) {
    const float* x      = (const float*)d_in[0];  // [16,2048,8]
    const float* params = (const float*)d_in[1];  // [8,3]
    const float* W1     = (const float*)d_in[2];  // [2048,8]
    const float* b1     = (const float*)d_in[3];  // [2048]
    const float* W2     = (const float*)d_in[4];  // [512,2048]
    const float* b2     = (const float*)d_in[5];  // [512]
    float* out = (float*)d_out;                   // [32768,512]

    char* ws = (char*)d_ws;
    __hip_bfloat16* W2b  = (__hip_bfloat16*)ws;              // 2 MB
    __hip_bfloat16* W1bg = (__hip_bfloat16*)(ws + 2097152);  // 32 KB

    k_prep<<<1040, 256, 0, stream>>>(W2, W1, W2b, W1bg);
    k_gemm<<<(NS/BM) * (EMB/BN), 256, 0, stream>>>(x, params, W1bg, b1, W2b, b2, out);
}